// Round 12
// baseline (730.007 us; speedup 1.0000x reference)
//
#include <hip/hip_runtime.h>
#include <hip/hip_bf16.h>
#include <stdint.h>

typedef __bf16 bf16_t;
typedef bf16_t bf16x8 __attribute__((ext_vector_type(8)));
typedef bf16_t bf16x4 __attribute__((ext_vector_type(4)));
typedef bf16_t bf16x2 __attribute__((ext_vector_type(2)));
typedef float f32x4 __attribute__((ext_vector_type(4)));
typedef uint32_t u32x4 __attribute__((ext_vector_type(4)));

// ---- workspace layout ----
// 0      : wq  bf16 [256][256]  (pre-scaled by 1/sqrt(32))
// 131072 : wkv bf16 [512][256]
// 393216 : wo  bf16 [256][256]
// 524288 : bias8 f32 [8][64][64]   ([h][q][k])
#define WS_WKV_OFF 65536   // elems
#define WS_WO_OFF  196608  // elems
#define WS_B8_OFF  524288  // bytes
#define QSCALE 0.17677669529663687f

__global__ __launch_bounds__(256) void prep_kernel(
    const float* __restrict__ wq, const float* __restrict__ wkv,
    const float* __restrict__ wo, const float* __restrict__ bt,
    const int* __restrict__ rp,
    bf16_t* __restrict__ wsq, bf16_t* __restrict__ wskv,
    bf16_t* __restrict__ wso, float* __restrict__ bias8) {
  int t = blockIdx.x * 256 + threadIdx.x;
  if (t < 65536)  wsq[t]  = (bf16_t)(wq[t] * QSCALE);
  if (t < 131072) wskv[t] = (bf16_t)wkv[t];
  if (t < 65536)  wso[t]  = (bf16_t)wo[t];
  if (t < 4096) {
    int idx = rp[t];
#pragma unroll
    for (int h = 0; h < 8; ++h) bias8[h * 4096 + t] = bt[idx * 8 + h];
  }
}

// 4-lane-group register transpose: build an MFMA A/B-frag (lane holds
// M[k=8*lgrp+j][n=16t+lrow], j=0..7) from packed C-frag pairs.
__device__ __forceinline__ bf16x8 xpose_frag(uint32_t e0, uint32_t e1,
                                             uint32_t o0, uint32_t o1,
                                             int ad0, int ad1, bool hi) {
  uint32_t v0e = (uint32_t)__builtin_amdgcn_ds_bpermute(ad0, (int)e0);
  uint32_t v0o = (uint32_t)__builtin_amdgcn_ds_bpermute(ad0, (int)o0);
  uint32_t v1e = (uint32_t)__builtin_amdgcn_ds_bpermute(ad0, (int)e1);
  uint32_t v1o = (uint32_t)__builtin_amdgcn_ds_bpermute(ad0, (int)o1);
  uint32_t v2e = (uint32_t)__builtin_amdgcn_ds_bpermute(ad1, (int)e0);
  uint32_t v2o = (uint32_t)__builtin_amdgcn_ds_bpermute(ad1, (int)o0);
  uint32_t v3e = (uint32_t)__builtin_amdgcn_ds_bpermute(ad1, (int)e1);
  uint32_t v3o = (uint32_t)__builtin_amdgcn_ds_bpermute(ad1, (int)o1);
  u32x4 r;
  r.x = hi ? v0o : v0e;
  r.y = hi ? v1o : v1e;
  r.z = hi ? v2o : v2e;
  r.w = hi ? v3o : v3e;
  return __builtin_bit_cast(bf16x8, r);
}

__device__ __forceinline__ uint32_t pk2(float a, float b) {
  bf16x2 t = {(bf16_t)a, (bf16_t)b};
  return __builtin_bit_cast(uint32_t, t);
}

// 256 threads = 4 waves; each wave handles heads wid (round 0) and wid+4
// (round 1). LDS: xs [64][264] (33792 B) + O0 buffer [64][132] (16896 B)
// = 50688 B -> 3 blocks/CU by LDS. Round-0 O goes straight to ldsO0 (waves
// own disjoint columns; final barrier orders readers). Round-1 O held in
// 16 packed regs, written to the xs overlay after the barrier.
// NO min-waves launch-bound: every bounded config (R3/5/8/10/11) triggered
// an arch-register cap + scratch spill. Plain (256) leaves the cap at 512.
__global__ __launch_bounds__(256) void win_attn_kernel(
    const float* __restrict__ x, const float* __restrict__ mask,
    const float* __restrict__ bq, const float* __restrict__ bkv,
    const float* __restrict__ bo,
    const bf16_t* __restrict__ wsq, const bf16_t* __restrict__ wskv,
    const bf16_t* __restrict__ wso, const float* __restrict__ bias8,
    float* __restrict__ out) {
  __shared__ bf16_t lds[64 * 264];
  __shared__ bf16_t ldsO0[64 * 132];
  const int b    = blockIdx.x;
  const int tid  = threadIdx.x;
  const int wid  = tid >> 6;
  const int lane = tid & 63;
  const int lrow = lane & 15;
  const int lgrp = lane >> 4;
  const bool hi  = (lgrp & 2) != 0;
  const int ad0  = ((((2 * lgrp) & 3) << 4) + lrow) << 2;
  const int ad1  = ((((2 * lgrp + 1) & 3) << 4) + lrow) << 2;
  const f32x4 zf = {0.f, 0.f, 0.f, 0.f};

  // ---- stage x (f32) -> bf16 LDS xs[64][264] ----
  {
    const float4* xv = (const float4*)(x + (size_t)b * 16384);
#pragma unroll
    for (int j = 0; j < 16; ++j) {
      int i4 = j * 256 + tid;
      float4 v = xv[i4];
      int e = i4 * 4;
      int r = e >> 8, c = e & 255;
      bf16x4 w = {(bf16_t)v.x, (bf16_t)v.y, (bf16_t)v.z, (bf16_t)v.w};
      *(bf16x4*)(lds + r * 264 + c) = w;
    }
  }
  __syncthreads();

  const float* maskw = mask + (size_t)(b & 1023) * 4096;
  uint32_t opk1[4][4];   // round-1 O only: [qt][dt*2+pr] packed bf16

#pragma unroll
  for (int rd = 0; rd < 2; ++rd) {
    const int h = wid + rd * 4;

    // ---- V-pass -> vb regs (two token-halves, acc=16) ----
    bf16x8 vb[2][2];
    {
      const bf16_t* WVh = wskv + (256 + h * 32) * 256;
      float bv0 = bkv[256 + h * 32 + lrow];
      float bv1 = bkv[256 + h * 32 + 16 + lrow];
#pragma unroll
      for (int vh = 0; vh < 2; ++vh) {
        f32x4 av[2][2];
        av[0][0] = av[0][1] = av[1][0] = av[1][1] = zf;
#pragma unroll
        for (int ks = 0; ks < 8; ++ks) {
          bf16x8 xa[2];
#pragma unroll
          for (int i = 0; i < 2; ++i)
            xa[i] = *(const bf16x8*)(lds + ((vh * 2 + i) * 16 + lrow) * 264 + ks * 32 + lgrp * 8);
          bf16x8 wvf[2];
#pragma unroll
          for (int tn = 0; tn < 2; ++tn)
            wvf[tn] = *(const bf16x8*)(WVh + (tn * 16 + lrow) * 256 + ks * 32 + lgrp * 8);
#pragma unroll
          for (int i = 0; i < 2; ++i)
#pragma unroll
            for (int tn = 0; tn < 2; ++tn)
              av[i][tn] = __builtin_amdgcn_mfma_f32_16x16x32_bf16(xa[i], wvf[tn], av[i][tn], 0, 0, 0);
        }
        uint32_t pkv[2][2][2];
#pragma unroll
        for (int i = 0; i < 2; ++i)
#pragma unroll
          for (int tn = 0; tn < 2; ++tn) {
            float bv = tn ? bv1 : bv0;
            pkv[i][tn][0] = pk2(av[i][tn][0] + bv, av[i][tn][1] + bv);
            pkv[i][tn][1] = pk2(av[i][tn][2] + bv, av[i][tn][3] + bv);
          }
#pragma unroll
        for (int dt = 0; dt < 2; ++dt)
          vb[dt][vh] = xpose_frag(pkv[0][dt][0], pkv[0][dt][1],
                                  pkv[1][dt][0], pkv[1][dt][1], ad0, ad1, hi);
      }
    }

    // ---- Q-pass -> qb (two half-n passes, acc=16) ----
    bf16x8 qb[4], ka[4];
    {
      const bf16_t* WQh = wsq + h * 32 * 256;
#pragma unroll
      for (int qh = 0; qh < 2; ++qh) {
        f32x4 aq[2][2];
        aq[0][0] = aq[0][1] = aq[1][0] = aq[1][1] = zf;
#pragma unroll
        for (int ks = 0; ks < 8; ++ks) {
          bf16x8 xb[2];
#pragma unroll
          for (int i = 0; i < 2; ++i)
            xb[i] = *(const bf16x8*)(lds + ((qh * 2 + i) * 16 + lrow) * 264 + ks * 32 + lgrp * 8);
          bf16x8 wqf[2];
#pragma unroll
          for (int tm = 0; tm < 2; ++tm)
            wqf[tm] = *(const bf16x8*)(WQh + (tm * 16 + lrow) * 256 + ks * 32 + lgrp * 8);
#pragma unroll
          for (int tm = 0; tm < 2; ++tm)
#pragma unroll
            for (int i = 0; i < 2; ++i)
              aq[tm][i] = __builtin_amdgcn_mfma_f32_16x16x32_bf16(wqf[tm], xb[i], aq[tm][i], 0, 0, 0);
        }
        uint32_t pq[2][2][2];
#pragma unroll
        for (int tm = 0; tm < 2; ++tm) {
          float4 b4 = *(const float4*)(bq + h * 32 + tm * 16 + lgrp * 4);
#pragma unroll
          for (int i = 0; i < 2; ++i) {
            pq[tm][i][0] = pk2(aq[tm][i][0] + b4.x * QSCALE, aq[tm][i][1] + b4.y * QSCALE);
            pq[tm][i][1] = pk2(aq[tm][i][2] + b4.z * QSCALE, aq[tm][i][3] + b4.w * QSCALE);
          }
        }
#pragma unroll
        for (int i = 0; i < 2; ++i)
          qb[qh * 2 + i] = xpose_frag(pq[0][i][0], pq[0][i][1], pq[1][i][0], pq[1][i][1], ad0, ad1, hi);
      }
    }
    // ---- K-pass -> ka (two half-n passes, acc=16) ----
    {
      const bf16_t* WKh = wskv + h * 32 * 256;
#pragma unroll
      for (int kh = 0; kh < 2; ++kh) {
        f32x4 ak2[2][2];
        ak2[0][0] = ak2[0][1] = ak2[1][0] = ak2[1][1] = zf;
#pragma unroll
        for (int ks = 0; ks < 8; ++ks) {
          bf16x8 xb[2];
#pragma unroll
          for (int i = 0; i < 2; ++i)
            xb[i] = *(const bf16x8*)(lds + ((kh * 2 + i) * 16 + lrow) * 264 + ks * 32 + lgrp * 8);
          bf16x8 wkf[2];
#pragma unroll
          for (int tm = 0; tm < 2; ++tm)
            wkf[tm] = *(const bf16x8*)(WKh + (tm * 16 + lrow) * 256 + ks * 32 + lgrp * 8);
#pragma unroll
          for (int tm = 0; tm < 2; ++tm)
#pragma unroll
            for (int i = 0; i < 2; ++i)
              ak2[tm][i] = __builtin_amdgcn_mfma_f32_16x16x32_bf16(wkf[tm], xb[i], ak2[tm][i], 0, 0, 0);
        }
        uint32_t pkk[2][2][2];
#pragma unroll
        for (int tm = 0; tm < 2; ++tm) {
          float4 k4 = *(const float4*)(bkv + h * 32 + tm * 16 + lgrp * 4);
#pragma unroll
          for (int i = 0; i < 2; ++i) {
            pkk[tm][i][0] = pk2(ak2[tm][i][0] + k4.x, ak2[tm][i][1] + k4.y);
            pkk[tm][i][1] = pk2(ak2[tm][i][2] + k4.z, ak2[tm][i][3] + k4.w);
          }
        }
#pragma unroll
        for (int i = 0; i < 2; ++i)
          ka[kh * 2 + i] = xpose_frag(pkk[0][i][0], pkk[0][i][1], pkk[1][i][0], pkk[1][i][1], ad0, ad1, hi);
      }
    }

    // ---- attention per q-tile ----
    const float* biash = bias8 + h * 4096;
#pragma unroll
    for (int qt = 0; qt < 4; ++qt) {
      f32x4 st[4];
#pragma unroll
      for (int tm = 0; tm < 4; ++tm)
        st[tm] = __builtin_amdgcn_mfma_f32_16x16x32_bf16(ka[tm], qb[qt], zf, 0, 0, 0);
      int q = qt * 16 + lrow;
      float sm = 0.f;
#pragma unroll
      for (int tm = 0; tm < 4; ++tm) {
        int kb = tm * 16 + lgrp * 4;
        float4 mb = *(const float4*)(maskw + q * 64 + kb);
        float4 bb = *(const float4*)(biash + q * 64 + kb);
#pragma unroll
        for (int r = 0; r < 4; ++r) {
          float madd = (r == 0) ? (mb.x + bb.x) : (r == 1) ? (mb.y + bb.y)
                     : (r == 2) ? (mb.z + bb.z) : (mb.w + bb.w);
          float p = __expf(st[tm][r] + madd);   // inputs bounded: no max-sub
          st[tm][r] = p;
          sm += p;
        }
      }
      sm += __shfl_xor(sm, 16);
      sm += __shfl_xor(sm, 32);
      float rs = 1.0f / sm;
      uint32_t ppk[4][2];
#pragma unroll
      for (int tm = 0; tm < 4; ++tm) {
        ppk[tm][0] = pk2(st[tm][0] * rs, st[tm][1] * rs);
        ppk[tm][1] = pk2(st[tm][2] * rs, st[tm][3] * rs);
      }
      bf16x8 paf[2];
#pragma unroll
      for (int kf = 0; kf < 2; ++kf)
        paf[kf] = xpose_frag(ppk[2 * kf][0], ppk[2 * kf][1],
                             ppk[2 * kf + 1][0], ppk[2 * kf + 1][1], ad0, ad1, hi);
      f32x4 o[2] = {zf, zf};
#pragma unroll
      for (int dt = 0; dt < 2; ++dt)
#pragma unroll
        for (int kf = 0; kf < 2; ++kf)
          o[dt] = __builtin_amdgcn_mfma_f32_16x16x32_bf16(paf[kf], vb[dt][kf], o[dt], 0, 0, 0);
      if (rd == 0) {
        // round-0 O -> ldsO0 (cols wid*32..wid*32+31); readers wait at the
        // final barrier, and this region aliases nothing.
#pragma unroll
        for (int dt = 0; dt < 2; ++dt)
#pragma unroll
          for (int r = 0; r < 4; ++r)
            ldsO0[(qt * 16 + lgrp * 4 + r) * 132 + wid * 32 + dt * 16 + lrow] =
                (bf16_t)o[dt][r];
      } else {
#pragma unroll
        for (int dt = 0; dt < 2; ++dt) {
          opk1[qt][dt * 2]     = pk2(o[dt][0], o[dt][1]);
          opk1[qt][dt * 2 + 1] = pk2(o[dt][2], o[dt][3]);
        }
      }
    }
  }

  // All xs reads done: round-1 O (global cols 128..255) overlays xs cols 0..127.
  __syncthreads();
  {
    int col0 = wid * 32;
#pragma unroll
    for (int qt = 0; qt < 4; ++qt)
#pragma unroll
      for (int dt = 0; dt < 2; ++dt)
#pragma unroll
        for (int pr = 0; pr < 2; ++pr) {
          bf16x2 t = __builtin_bit_cast(bf16x2, opk1[qt][dt * 2 + pr]);
          int row = qt * 16 + lgrp * 4 + 2 * pr;
          int col = col0 + dt * 16 + lrow;
          lds[row * 264 + col] = t[0];
          lds[(row + 1) * 264 + col] = t[1];
        }
  }
  __syncthreads();

  // ---- out-projection: wave w owns rows w*16..w*16+16; 4 col-phases.
  // O cols 0..127 in ldsO0; cols 128..255 in lds overlay (offset col-128).
  float* outw = out + (size_t)b * 16384;
#pragma unroll
  for (int cp = 0; cp < 4; ++cp) {
    f32x4 acc[4];
#pragma unroll
    for (int tn = 0; tn < 4; ++tn) acc[tn] = zf;
#pragma unroll
    for (int ks = 0; ks < 8; ++ks) {
      bf16x8 ao;
      if (ks < 4)
        ao = *(const bf16x8*)(ldsO0 + (wid * 16 + lrow) * 132 + ks * 32 + lgrp * 8);
      else
        ao = *(const bf16x8*)(lds + (wid * 16 + lrow) * 264 + (ks - 4) * 32 + lgrp * 8);
#pragma unroll
      for (int tn = 0; tn < 4; ++tn) {
        bf16x8 bw = *(const bf16x8*)(wso + (cp * 64 + tn * 16 + lrow) * 256 + ks * 32 + lgrp * 8);
        acc[tn] = __builtin_amdgcn_mfma_f32_16x16x32_bf16(ao, bw, acc[tn], 0, 0, 0);
      }
    }
#pragma unroll
    for (int tn = 0; tn < 4; ++tn) {
      float bov = bo[cp * 64 + tn * 16 + lrow];
#pragma unroll
      for (int r = 0; r < 4; ++r)
        outw[(wid * 16 + lgrp * 4 + r) * 256 + cp * 64 + tn * 16 + lrow] = acc[tn][r] + bov;
    }
  }
}

extern "C" void kernel_launch(void* const* d_in, const int* in_sizes, int n_in,
                              void* d_out, int out_size, void* d_ws, size_t ws_size,
                              hipStream_t stream) {
  const float* x    = (const float*)d_in[0];
  const float* mask = (const float*)d_in[1];
  const float* wq   = (const float*)d_in[2];
  const float* bq   = (const float*)d_in[3];
  const float* wkv  = (const float*)d_in[4];
  const float* bkv  = (const float*)d_in[5];
  const float* bt   = (const float*)d_in[6];
  const float* wo   = (const float*)d_in[7];
  const float* bo   = (const float*)d_in[8];
  const int*   rp   = (const int*)d_in[9];
  float* out = (float*)d_out;

  bf16_t* wsq  = (bf16_t*)d_ws;
  bf16_t* wskv = wsq + WS_WKV_OFF;
  bf16_t* wso  = wsq + WS_WO_OFF;
  float*  bias8 = (float*)((char*)d_ws + WS_B8_OFF);

  prep_kernel<<<512, 256, 0, stream>>>(wq, wkv, wo, bt, rp, wsq, wskv, wso, bias8);

  win_attn_kernel<<<4096, 256, 0, stream>>>(
      x, mask, bq, bkv, bo, wsq, wskv, wso, bias8, out);
}

// Round 13
// 607.481 us; speedup vs baseline: 1.2017x; 1.2017x over previous
//
#include <hip/hip_runtime.h>
#include <hip/hip_bf16.h>
#include <stdint.h>

typedef __bf16 bf16_t;
typedef bf16_t bf16x8 __attribute__((ext_vector_type(8)));
typedef bf16_t bf16x4 __attribute__((ext_vector_type(4)));
typedef bf16_t bf16x2 __attribute__((ext_vector_type(2)));
typedef float f32x4 __attribute__((ext_vector_type(4)));
typedef uint32_t u32x4 __attribute__((ext_vector_type(4)));

// ---- workspace layout ----
#define WS_WKV_OFF 65536   // elems
#define WS_WO_OFF  196608  // elems
#define WS_B8_OFF  524288  // bytes
#define QSCALE 0.17677669529663687f

__global__ __launch_bounds__(256) void prep_kernel(
    const float* __restrict__ wq, const float* __restrict__ wkv,
    const float* __restrict__ wo, const float* __restrict__ bt,
    const int* __restrict__ rp,
    bf16_t* __restrict__ wsq, bf16_t* __restrict__ wskv,
    bf16_t* __restrict__ wso, float* __restrict__ bias8) {
  int t = blockIdx.x * 256 + threadIdx.x;
  if (t < 65536)  wsq[t]  = (bf16_t)(wq[t] * QSCALE);
  if (t < 131072) wskv[t] = (bf16_t)wkv[t];
  if (t < 65536)  wso[t]  = (bf16_t)wo[t];
  if (t < 4096) {
    int idx = rp[t];
#pragma unroll
    for (int h = 0; h < 8; ++h) bias8[h * 4096 + t] = bt[idx * 8 + h];
  }
}

__device__ __forceinline__ bf16x8 xpose_frag(uint32_t e0, uint32_t e1,
                                             uint32_t o0, uint32_t o1,
                                             int ad0, int ad1, bool hi) {
  uint32_t v0e = (uint32_t)__builtin_amdgcn_ds_bpermute(ad0, (int)e0);
  uint32_t v0o = (uint32_t)__builtin_amdgcn_ds_bpermute(ad0, (int)o0);
  uint32_t v1e = (uint32_t)__builtin_amdgcn_ds_bpermute(ad0, (int)e1);
  uint32_t v1o = (uint32_t)__builtin_amdgcn_ds_bpermute(ad0, (int)o1);
  uint32_t v2e = (uint32_t)__builtin_amdgcn_ds_bpermute(ad1, (int)e0);
  uint32_t v2o = (uint32_t)__builtin_amdgcn_ds_bpermute(ad1, (int)o0);
  uint32_t v3e = (uint32_t)__builtin_amdgcn_ds_bpermute(ad1, (int)e1);
  uint32_t v3o = (uint32_t)__builtin_amdgcn_ds_bpermute(ad1, (int)o1);
  u32x4 r;
  r.x = hi ? v0o : v0e;
  r.y = hi ? v1o : v1e;
  r.z = hi ? v2o : v2e;
  r.w = hi ? v3o : v3e;
  return __builtin_bit_cast(bf16x8, r);
}

__device__ __forceinline__ uint32_t pk2(float a, float b) {
  bf16x2 t = {(bf16_t)a, (bf16_t)b};
  return __builtin_bit_cast(uint32_t, t);
}

// 256 threads = 4 waves; each wave handles heads wid (round 0) and wid+4
// (round 1). LDS: xs [64][264] + O0 [64][132] = 50688 B -> 3 blocks/CU.
// (256,3): total budget 170/wave. Accumulator-carrying OUTER loops are
// `#pragma unroll 1` so acc tiles are reused serially (AGPR ~16-24), leaving
// the arch side ~145 -- fits without scratch. Inner ks loops stay unrolled.
__global__ __launch_bounds__(256, 3) void win_attn_kernel(
    const float* __restrict__ x, const float* __restrict__ mask,
    const float* __restrict__ bq, const float* __restrict__ bkv,
    const float* __restrict__ bo,
    const bf16_t* __restrict__ wsq, const bf16_t* __restrict__ wskv,
    const bf16_t* __restrict__ wso, const float* __restrict__ bias8,
    float* __restrict__ out) {
  __shared__ bf16_t lds[64 * 264];
  __shared__ bf16_t ldsO0[64 * 132];
  const int b    = blockIdx.x;
  const int tid  = threadIdx.x;
  const int wid  = tid >> 6;
  const int lane = tid & 63;
  const int lrow = lane & 15;
  const int lgrp = lane >> 4;
  const bool hi  = (lgrp & 2) != 0;
  const int ad0  = ((((2 * lgrp) & 3) << 4) + lrow) << 2;
  const int ad1  = ((((2 * lgrp + 1) & 3) << 4) + lrow) << 2;
  const f32x4 zf = {0.f, 0.f, 0.f, 0.f};

  // ---- stage x (f32) -> bf16 LDS xs[64][264] ----
  {
    const float4* xv = (const float4*)(x + (size_t)b * 16384);
#pragma unroll
    for (int j = 0; j < 16; ++j) {
      int i4 = j * 256 + tid;
      float4 v = xv[i4];
      int e = i4 * 4;
      int r = e >> 8, c = e & 255;
      bf16x4 w = {(bf16_t)v.x, (bf16_t)v.y, (bf16_t)v.z, (bf16_t)v.w};
      *(bf16x4*)(lds + r * 264 + c) = w;
    }
  }
  __syncthreads();

  const float* maskw = mask + (size_t)(b & 1023) * 4096;
  uint32_t opk1[4][4];   // round-1 O only: [qt][dt*2+pr] packed bf16

#pragma unroll 1
  for (int rd = 0; rd < 2; ++rd) {
    const int h = wid + rd * 4;

    // ---- V-pass -> vb regs (two token-halves, acc=16) ----
    bf16x8 vb[2][2];
    {
      const bf16_t* WVh = wskv + (256 + h * 32) * 256;
      float bv0 = bkv[256 + h * 32 + lrow];
      float bv1 = bkv[256 + h * 32 + 16 + lrow];
#pragma unroll 1
      for (int vh = 0; vh < 2; ++vh) {
        f32x4 av[2][2];
        av[0][0] = av[0][1] = av[1][0] = av[1][1] = zf;
#pragma unroll
        for (int ks = 0; ks < 8; ++ks) {
          bf16x8 xa[2];
#pragma unroll
          for (int i = 0; i < 2; ++i)
            xa[i] = *(const bf16x8*)(lds + ((vh * 2 + i) * 16 + lrow) * 264 + ks * 32 + lgrp * 8);
          bf16x8 wvf[2];
#pragma unroll
          for (int tn = 0; tn < 2; ++tn)
            wvf[tn] = *(const bf16x8*)(WVh + (tn * 16 + lrow) * 256 + ks * 32 + lgrp * 8);
#pragma unroll
          for (int i = 0; i < 2; ++i)
#pragma unroll
            for (int tn = 0; tn < 2; ++tn)
              av[i][tn] = __builtin_amdgcn_mfma_f32_16x16x32_bf16(xa[i], wvf[tn], av[i][tn], 0, 0, 0);
        }
        uint32_t pkv[2][2][2];
#pragma unroll
        for (int i = 0; i < 2; ++i)
#pragma unroll
          for (int tn = 0; tn < 2; ++tn) {
            float bv = tn ? bv1 : bv0;
            pkv[i][tn][0] = pk2(av[i][tn][0] + bv, av[i][tn][1] + bv);
            pkv[i][tn][1] = pk2(av[i][tn][2] + bv, av[i][tn][3] + bv);
          }
#pragma unroll
        for (int dt = 0; dt < 2; ++dt)
          vb[dt][vh] = xpose_frag(pkv[0][dt][0], pkv[0][dt][1],
                                  pkv[1][dt][0], pkv[1][dt][1], ad0, ad1, hi);
      }
    }

    // ---- Q-pass -> qb (two half-n passes, acc=16) ----
    bf16x8 qb[4], ka[4];
    {
      const bf16_t* WQh = wsq + h * 32 * 256;
#pragma unroll 1
      for (int qh = 0; qh < 2; ++qh) {
        f32x4 aq[2][2];
        aq[0][0] = aq[0][1] = aq[1][0] = aq[1][1] = zf;
#pragma unroll
        for (int ks = 0; ks < 8; ++ks) {
          bf16x8 xb[2];
#pragma unroll
          for (int i = 0; i < 2; ++i)
            xb[i] = *(const bf16x8*)(lds + ((qh * 2 + i) * 16 + lrow) * 264 + ks * 32 + lgrp * 8);
          bf16x8 wqf[2];
#pragma unroll
          for (int tm = 0; tm < 2; ++tm)
            wqf[tm] = *(const bf16x8*)(WQh + (tm * 16 + lrow) * 256 + ks * 32 + lgrp * 8);
#pragma unroll
          for (int tm = 0; tm < 2; ++tm)
#pragma unroll
            for (int i = 0; i < 2; ++i)
              aq[tm][i] = __builtin_amdgcn_mfma_f32_16x16x32_bf16(wqf[tm], xb[i], aq[tm][i], 0, 0, 0);
        }
        uint32_t pq[2][2][2];
#pragma unroll
        for (int tm = 0; tm < 2; ++tm) {
          float4 b4 = *(const float4*)(bq + h * 32 + tm * 16 + lgrp * 4);
#pragma unroll
          for (int i = 0; i < 2; ++i) {
            pq[tm][i][0] = pk2(aq[tm][i][0] + b4.x * QSCALE, aq[tm][i][1] + b4.y * QSCALE);
            pq[tm][i][1] = pk2(aq[tm][i][2] + b4.z * QSCALE, aq[tm][i][3] + b4.w * QSCALE);
          }
        }
#pragma unroll
        for (int i = 0; i < 2; ++i)
          qb[qh * 2 + i] = xpose_frag(pq[0][i][0], pq[0][i][1], pq[1][i][0], pq[1][i][1], ad0, ad1, hi);
      }
    }
    // ---- K-pass -> ka (two half-n passes, acc=16) ----
    {
      const bf16_t* WKh = wskv + h * 32 * 256;
#pragma unroll 1
      for (int kh = 0; kh < 2; ++kh) {
        f32x4 ak2[2][2];
        ak2[0][0] = ak2[0][1] = ak2[1][0] = ak2[1][1] = zf;
#pragma unroll
        for (int ks = 0; ks < 8; ++ks) {
          bf16x8 xb[2];
#pragma unroll
          for (int i = 0; i < 2; ++i)
            xb[i] = *(const bf16x8*)(lds + ((kh * 2 + i) * 16 + lrow) * 264 + ks * 32 + lgrp * 8);
          bf16x8 wkf[2];
#pragma unroll
          for (int tm = 0; tm < 2; ++tm)
            wkf[tm] = *(const bf16x8*)(WKh + (tm * 16 + lrow) * 256 + ks * 32 + lgrp * 8);
#pragma unroll
          for (int tm = 0; tm < 2; ++tm)
#pragma unroll
            for (int i = 0; i < 2; ++i)
              ak2[tm][i] = __builtin_amdgcn_mfma_f32_16x16x32_bf16(wkf[tm], xb[i], ak2[tm][i], 0, 0, 0);
        }
        uint32_t pkk[2][2][2];
#pragma unroll
        for (int tm = 0; tm < 2; ++tm) {
          float4 k4 = *(const float4*)(bkv + h * 32 + tm * 16 + lgrp * 4);
#pragma unroll
          for (int i = 0; i < 2; ++i) {
            pkk[tm][i][0] = pk2(ak2[tm][i][0] + k4.x, ak2[tm][i][1] + k4.y);
            pkk[tm][i][1] = pk2(ak2[tm][i][2] + k4.z, ak2[tm][i][3] + k4.w);
          }
        }
#pragma unroll
        for (int i = 0; i < 2; ++i)
          ka[kh * 2 + i] = xpose_frag(pkk[0][i][0], pkk[0][i][1], pkk[1][i][0], pkk[1][i][1], ad0, ad1, hi);
      }
    }

    // ---- attention per q-tile (serialized: acc reused) ----
    const float* biash = bias8 + h * 4096;
#pragma unroll 1
    for (int qt = 0; qt < 4; ++qt) {
      f32x4 st[4];
#pragma unroll
      for (int tm = 0; tm < 4; ++tm)
        st[tm] = __builtin_amdgcn_mfma_f32_16x16x32_bf16(ka[tm], qb[qt], zf, 0, 0, 0);
      int q = qt * 16 + lrow;
      float sm = 0.f;
#pragma unroll
      for (int tm = 0; tm < 4; ++tm) {
        int kb = tm * 16 + lgrp * 4;
        float4 mb = *(const float4*)(maskw + q * 64 + kb);
        float4 bb = *(const float4*)(biash + q * 64 + kb);
#pragma unroll
        for (int r = 0; r < 4; ++r) {
          float madd = (r == 0) ? (mb.x + bb.x) : (r == 1) ? (mb.y + bb.y)
                     : (r == 2) ? (mb.z + bb.z) : (mb.w + bb.w);
          float p = __expf(st[tm][r] + madd);   // inputs bounded: no max-sub
          st[tm][r] = p;
          sm += p;
        }
      }
      sm += __shfl_xor(sm, 16);
      sm += __shfl_xor(sm, 32);
      float rs = 1.0f / sm;
      uint32_t ppk[4][2];
#pragma unroll
      for (int tm = 0; tm < 4; ++tm) {
        ppk[tm][0] = pk2(st[tm][0] * rs, st[tm][1] * rs);
        ppk[tm][1] = pk2(st[tm][2] * rs, st[tm][3] * rs);
      }
      bf16x8 paf[2];
#pragma unroll
      for (int kf = 0; kf < 2; ++kf)
        paf[kf] = xpose_frag(ppk[2 * kf][0], ppk[2 * kf][1],
                             ppk[2 * kf + 1][0], ppk[2 * kf + 1][1], ad0, ad1, hi);
      f32x4 o[2] = {zf, zf};
#pragma unroll
      for (int dt = 0; dt < 2; ++dt)
#pragma unroll
        for (int kf = 0; kf < 2; ++kf)
          o[dt] = __builtin_amdgcn_mfma_f32_16x16x32_bf16(paf[kf], vb[dt][kf], o[dt], 0, 0, 0);
      if (rd == 0) {
#pragma unroll
        for (int dt = 0; dt < 2; ++dt)
#pragma unroll
          for (int r = 0; r < 4; ++r)
            ldsO0[(qt * 16 + lgrp * 4 + r) * 132 + wid * 32 + dt * 16 + lrow] =
                (bf16_t)o[dt][r];
      } else {
#pragma unroll
        for (int dt = 0; dt < 2; ++dt) {
          opk1[qt][dt * 2]     = pk2(o[dt][0], o[dt][1]);
          opk1[qt][dt * 2 + 1] = pk2(o[dt][2], o[dt][3]);
        }
      }
    }
  }

  // All xs reads done: round-1 O (global cols 128..255) overlays xs cols 0..127.
  __syncthreads();
  {
    int col0 = wid * 32;
#pragma unroll
    for (int qt = 0; qt < 4; ++qt)
#pragma unroll
      for (int dt = 0; dt < 2; ++dt)
#pragma unroll
        for (int pr = 0; pr < 2; ++pr) {
          bf16x2 t = __builtin_bit_cast(bf16x2, opk1[qt][dt * 2 + pr]);
          int row = qt * 16 + lgrp * 4 + 2 * pr;
          int col = col0 + dt * 16 + lrow;
          lds[row * 264 + col] = t[0];
          lds[(row + 1) * 264 + col] = t[1];
        }
  }
  __syncthreads();

  // ---- out-projection: wave w owns rows w*16..w*16+16; 4 col-phases ----
  float* outw = out + (size_t)b * 16384;
#pragma unroll 1
  for (int cp = 0; cp < 4; ++cp) {
    f32x4 acc[4];
#pragma unroll
    for (int tn = 0; tn < 4; ++tn) acc[tn] = zf;
#pragma unroll
    for (int ks = 0; ks < 8; ++ks) {
      bf16x8 ao;
      if (ks < 4)
        ao = *(const bf16x8*)(ldsO0 + (wid * 16 + lrow) * 132 + ks * 32 + lgrp * 8);
      else
        ao = *(const bf16x8*)(lds + (wid * 16 + lrow) * 264 + (ks - 4) * 32 + lgrp * 8);
#pragma unroll
      for (int tn = 0; tn < 4; ++tn) {
        bf16x8 bw = *(const bf16x8*)(wso + (cp * 64 + tn * 16 + lrow) * 256 + ks * 32 + lgrp * 8);
        acc[tn] = __builtin_amdgcn_mfma_f32_16x16x32_bf16(ao, bw, acc[tn], 0, 0, 0);
      }
    }
#pragma unroll
    for (int tn = 0; tn < 4; ++tn) {
      float bov = bo[cp * 64 + tn * 16 + lrow];
#pragma unroll
      for (int r = 0; r < 4; ++r)
        outw[(wid * 16 + lgrp * 4 + r) * 256 + cp * 64 + tn * 16 + lrow] = acc[tn][r] + bov;
    }
  }
}

extern "C" void kernel_launch(void* const* d_in, const int* in_sizes, int n_in,
                              void* d_out, int out_size, void* d_ws, size_t ws_size,
                              hipStream_t stream) {
  const float* x    = (const float*)d_in[0];
  const float* mask = (const float*)d_in[1];
  const float* wq   = (const float*)d_in[2];
  const float* bq   = (const float*)d_in[3];
  const float* wkv  = (const float*)d_in[4];
  const float* bkv  = (const float*)d_in[5];
  const float* bt   = (const float*)d_in[6];
  const float* wo   = (const float*)d_in[7];
  const float* bo   = (const float*)d_in[8];
  const int*   rp   = (const int*)d_in[9];
  float* out = (float*)d_out;

  bf16_t* wsq  = (bf16_t*)d_ws;
  bf16_t* wskv = wsq + WS_WKV_OFF;
  bf16_t* wso  = wsq + WS_WO_OFF;
  float*  bias8 = (float*)((char*)d_ws + WS_B8_OFF);

  prep_kernel<<<512, 256, 0, stream>>>(wq, wkv, wo, bt, rp, wsq, wskv, wso, bias8);

  win_attn_kernel<<<4096, 256, 0, stream>>>(
      x, mask, bq, bkv, bo, wsq, wskv, wso, bias8, out);
}